// Round 2
// baseline (375.700 us; speedup 1.0000x reference)
//
#include <hip/hip_runtime.h>

typedef unsigned int u32;

#define LOG2E 1.4426950408889634f
#define LN2   0.6931471805599453f

// weight offsets inside s_w (floats)
#define LW   0
#define LB   8
#define IPW  16
#define CW   272
#define CB   336
#define XPW  352
#define DTW  880
#define DTB  896
#define DSK  912
#define OW   928
#define BWo  1056
#define BBo  1120
#define WTOT 1128

__device__ __forceinline__ float fexp2(float x){ return __builtin_amdgcn_exp2f(x); }
__device__ __forceinline__ float flog2(float x){ return __builtin_amdgcn_logf(x); }
__device__ __forceinline__ float frcp (float x){ return __builtin_amdgcn_rcpf(x); }
__device__ __forceinline__ float siluf(float x){ return x * frcp(1.0f + fexp2(-x * LOG2E)); }
__device__ __forceinline__ float softplusf(float x){
  float r = flog2(1.0f + fexp2(x * LOG2E)) * LN2;
  return x > 15.0f ? x : r;
}

// one wave (64 threads) per (channel c, sequence n); Lf=256 processed in 4 chunks of 64
__global__ __launch_bounds__(64) void mamba_k(
    const float* __restrict__ xg,   const float* __restrict__ lwg,  const float* __restrict__ lbg,
    const float* __restrict__ ipwg, const float* __restrict__ cwg,  const float* __restrict__ cbg,
    const float* __restrict__ xpwg, const float* __restrict__ dtwg, const float* __restrict__ dtbg,
    const float* __restrict__ alogg,const float* __restrict__ dskg, const float* __restrict__ owg,
    const float* __restrict__ bwg,  const float* __restrict__ bbg,  float* __restrict__ feat)
{
  __shared__ __align__(16) float s_w[WTOT];     // channel weights
  __shared__ __align__(16) float s_B[64*20];    // stride 20: 16B-aligned rows for float4 scan reads
  __shared__ __align__(16) float s_C[64*20];
  __shared__ __align__(16) float s_xc[64*17];   // stride 17: odd -> conflict-free row-parallel access
  __shared__ __align__(16) float s_dt[64*17];
  __shared__ __align__(16) float s_xin[67*17];  // 3 history rows + 64
  __shared__ __align__(16) float s_zg[64*17];
  __shared__ __align__(16) float s_y[64*17];

  const int lane = threadIdx.x;
  const int bid  = blockIdx.x;
  const int c    = bid & 7;        // consecutive bids share n -> x cache-line reuse
  const int n    = bid >> 3;
  const int bb_  = n >> 7;
  const int ls   = n & 127;
  const int di   = lane >> 2;      // scan: lane owns (di, 4 states)
  const int sg   = lane & 3;

  // ---- stage channel weights into LDS ----
  for (int i = lane; i < 256; i += 64) s_w[IPW+i] = ipwg[c*256+i];
  for (int i = lane; i < 528; i += 64) s_w[XPW+i] = xpwg[c*528+i];
  for (int i = lane; i < 128; i += 64) s_w[OW+i]  = owg[c*128+i];
  { s_w[CW+lane] = cwg[c*64+lane]; s_w[BWo+lane] = bwg[c*64+lane]; }
  if (lane < 16) {
    s_w[CB+lane]  = cbg [c*16+lane];
    s_w[DTW+lane] = dtwg[c*16+lane];
    s_w[DTB+lane] = dtbg[c*16+lane];
    s_w[DSK+lane] = dskg[c*16+lane];
  }
  if (lane < 8) {
    s_w[LW+lane]  = lwg[c*8+lane];
    s_w[LB+lane]  = lbg[c*8+lane];
    s_w[BBo+lane] = bbg[c*8+lane];
  }
  if (lane < 48) { int r = lane >> 4, col = lane & 15; s_xin[r*17+col] = 0.f; }  // conv zero-pad history

  // per-lane A (pre-scaled by log2e so dA = exp2(dt*Am))
  float Am0, Am1, Am2, Am3;
  {
    const int ab = c*256 + di*16 + sg*4;
    Am0 = -fexp2(alogg[ab+0] * LOG2E) * LOG2E;
    Am1 = -fexp2(alogg[ab+1] * LOG2E) * LOG2E;
    Am2 = -fexp2(alogg[ab+2] * LOG2E) * LOG2E;
    Am3 = -fexp2(alogg[ab+3] * LOG2E) * LOG2E;
  }
  __syncthreads();

  float h0 = 0.f, h1 = 0.f, h2 = 0.f, h3 = 0.f;   // scan state persists across chunks
  float pacc[8];
  #pragma unroll
  for (int d = 0; d < 8; ++d) pacc[d] = 0.f;

  const int xbase = bb_*262144 + ls*8 + c;

  #pragma unroll 1
  for (int ch = 0; ch < 4; ++ch) {
    if (ch > 0) {
      __syncthreads();  // previous post-pass done before we overwrite LDS
      if (lane < 48) { int r = lane >> 4, col = lane & 15; s_xin[r*17+col] = s_xin[(64+r)*17+col]; }
      __syncthreads();
    }
    // ---- phase A1: lift + in_proj (lane = t) ----
    {
      const int t = ch*64 + lane;
      const float xval = xg[xbase + t*1024];
      float z[8];
      #pragma unroll
      for (int d = 0; d < 8; ++d) z[d] = xval * s_w[LW+d] + s_w[LB+d];
      const float* ip = s_w + IPW;
      float* xrow = s_xin + (3+lane)*17;
      float* zrow = s_zg + lane*17;
      #pragma unroll
      for (int j = 0; j < 16; ++j) {
        float4 w0 = *(const float4*)(ip + j*8);
        float4 w1 = *(const float4*)(ip + j*8 + 4);
        xrow[j] = z[0]*w0.x + z[1]*w0.y + z[2]*w0.z + z[3]*w0.w
                + z[4]*w1.x + z[5]*w1.y + z[6]*w1.z + z[7]*w1.w;
      }
      #pragma unroll
      for (int j = 0; j < 16; ++j) {
        float4 w0 = *(const float4*)(ip + 128 + j*8);
        float4 w1 = *(const float4*)(ip + 128 + j*8 + 4);
        zrow[j] = z[0]*w0.x + z[1]*w0.y + z[2]*w0.z + z[3]*w0.w
                + z[4]*w1.x + z[5]*w1.y + z[6]*w1.z + z[7]*w1.w;
      }
    }
    __syncthreads();
    // ---- phase A2: depthwise conv + SiLU + x_proj + dt (lane = t) ----
    {
      float xc[16];
      #pragma unroll
      for (int i = 0; i < 16; ++i) xc[i] = s_w[CB+i];
      #pragma unroll
      for (int k = 0; k < 4; ++k) {
        const float* row = s_xin + (lane+k)*17;
        #pragma unroll
        for (int i = 0; i < 16; ++i) xc[i] += row[i] * s_w[CW + i*4 + k];
      }
      #pragma unroll
      for (int i = 0; i < 16; ++i) xc[i] = siluf(xc[i]);
      {
        float* xcrow = s_xc + lane*17;
        #pragma unroll
        for (int i = 0; i < 16; ++i) xcrow[i] = xc[i];
      }
      const float* xp = s_w + XPW;
      float dtlo;
      {
        float acc = 0.f;
        #pragma unroll
        for (int q = 0; q < 4; ++q) {
          float4 w = *(const float4*)(xp + q*4);
          acc += xc[q*4+0]*w.x + xc[q*4+1]*w.y + xc[q*4+2]*w.z + xc[q*4+3]*w.w;
        }
        dtlo = acc;
      }
      float* Brow = s_B + lane*20;
      float* Crow = s_C + lane*20;
      #pragma unroll
      for (int r = 1; r < 17; ++r) {
        float acc = 0.f;
        #pragma unroll
        for (int q = 0; q < 4; ++q) {
          float4 w = *(const float4*)(xp + r*16 + q*4);
          acc += xc[q*4+0]*w.x + xc[q*4+1]*w.y + xc[q*4+2]*w.z + xc[q*4+3]*w.w;
        }
        Brow[r-1] = acc;
      }
      #pragma unroll
      for (int r = 17; r < 33; ++r) {
        float acc = 0.f;
        #pragma unroll
        for (int q = 0; q < 4; ++q) {
          float4 w = *(const float4*)(xp + r*16 + q*4);
          acc += xc[q*4+0]*w.x + xc[q*4+1]*w.y + xc[q*4+2]*w.z + xc[q*4+3]*w.w;
        }
        Crow[r-17] = acc;
      }
      float* dtrow = s_dt + lane*17;
      #pragma unroll
      for (int i = 0; i < 16; ++i) dtrow[i] = softplusf(dtlo * s_w[DTW+i] + s_w[DTB+i]);
    }
    __syncthreads();
    // ---- scan: 64 sequential steps, 4 f32 states/lane in regs ----
    {
      const float* pB  = s_B + sg*4;
      const float* pC  = s_C + sg*4;
      const float* pdt = s_dt + di;
      const float* pxc = s_xc + di;
      float* py = s_y + di;
      #pragma unroll 4
      for (int tl = 0; tl < 64; ++tl) {
        float4 bv = *(const float4*)pB;     // same-row broadcast reads: conflict-free
        float4 cv = *(const float4*)pC;
        float dtv = *pdt;
        float xcv = *pxc;
        float w = dtv * xcv;
        float e0 = fexp2(dtv*Am0);
        float e1 = fexp2(dtv*Am1);
        float e2 = fexp2(dtv*Am2);
        float e3 = fexp2(dtv*Am3);
        h0 = h0*e0 + w*bv.x;
        h1 = h1*e1 + w*bv.y;
        h2 = h2*e2 + w*bv.z;
        h3 = h3*e3 + w*bv.w;
        float yp = h0*cv.x + h1*cv.y + h2*cv.z + h3*cv.w;
        yp += __shfl_xor(yp, 1);   // reduce over the 4-lane s-quad
        yp += __shfl_xor(yp, 2);
        if (sg == 0) *py = yp;
        pB += 20; pC += 20; pdt += 17; pxc += 17; py += 17;
      }
    }
    __syncthreads();
    // ---- post: gate + out/blk projections + pooled accumulate (lane = t) ----
    {
      const float* yrow  = s_y  + lane*17;
      const float* xcrow = s_xc + lane*17;
      const float* zrow  = s_zg + lane*17;
      float yf[16];
      #pragma unroll
      for (int i = 0; i < 16; ++i) {
        float g = siluf(zrow[i]);
        yf[i] = (yrow[i] + s_w[DSK+i]*xcrow[i]) * g;
      }
      float outv[8];
      #pragma unroll
      for (int d = 0; d < 8; ++d) {
        const float* wr = s_w + OW + d*16;
        float acc = 0.f;
        #pragma unroll
        for (int q = 0; q < 4; ++q) {
          float4 w = *(const float4*)(wr + q*4);
          acc += yf[q*4+0]*w.x + yf[q*4+1]*w.y + yf[q*4+2]*w.z + yf[q*4+3]*w.w;
        }
        outv[d] = acc;
      }
      #pragma unroll
      for (int d = 0; d < 8; ++d) {
        const float* wr = s_w + BWo + d*8;
        float4 w0 = *(const float4*)(wr);
        float4 w1 = *(const float4*)(wr + 4);
        float acc = s_w[BBo+d]
          + outv[0]*w0.x + outv[1]*w0.y + outv[2]*w0.z + outv[3]*w0.w
          + outv[4]*w1.x + outv[5]*w1.y + outv[6]*w1.z + outv[7]*w1.w;
        pacc[d] += siluf(acc);
      }
    }
  }

  // ---- reduce pooled over 64 lanes, write feat[n][c*8+d] ----
  #pragma unroll
  for (int d = 0; d < 8; ++d) {
    float v = pacc[d];
    v += __shfl_xor(v, 1);
    v += __shfl_xor(v, 2);
    v += __shfl_xor(v, 4);
    v += __shfl_xor(v, 8);
    v += __shfl_xor(v, 16);
    v += __shfl_xor(v, 32);
    pacc[d] = v;
  }
  if (lane == 0) {
    #pragma unroll
    for (int d = 0; d < 8; ++d) feat[n*64 + c*8 + d] = pacc[d] * (1.0f/256.0f);
  }
}

// LayerNorm over the 64-wide feature dim; one wave per row
__global__ __launch_bounds__(64) void ln_k(const float* __restrict__ feat,
    const float* __restrict__ g, const float* __restrict__ b, float* __restrict__ out)
{
  const int row = blockIdx.x;
  const int l = threadIdx.x;
  float v = feat[row*64 + l];
  float s = v, q = v*v;
  #pragma unroll
  for (int m = 1; m < 64; m <<= 1) { s += __shfl_xor(s, m); q += __shfl_xor(q, m); }
  float mu  = s * (1.0f/64.0f);
  float var = q * (1.0f/64.0f) - mu*mu;
  float rs  = __builtin_amdgcn_rsqf(var + 1e-5f);
  out[row*64 + l] = (v - mu) * rs * g[l] + b[l];
}

extern "C" void kernel_launch(void* const* d_in, const int* in_sizes, int n_in,
                              void* d_out, int out_size, void* d_ws, size_t ws_size,
                              hipStream_t stream)
{
  const float* xg    = (const float*)d_in[0];
  const float* lwg   = (const float*)d_in[1];
  const float* lbg   = (const float*)d_in[2];
  const float* ipwg  = (const float*)d_in[3];
  const float* cwg   = (const float*)d_in[4];
  const float* cbg   = (const float*)d_in[5];
  const float* xpwg  = (const float*)d_in[6];
  const float* dtwg  = (const float*)d_in[7];
  const float* dtbg  = (const float*)d_in[8];
  const float* alogg = (const float*)d_in[9];
  const float* dskg  = (const float*)d_in[10];
  const float* owg   = (const float*)d_in[11];
  const float* bwg   = (const float*)d_in[12];
  const float* bbg   = (const float*)d_in[13];
  const float* lng   = (const float*)d_in[14];
  const float* lnb   = (const float*)d_in[15];
  float* feat = (float*)d_ws;   // 512*64 f32 = 128 KB scratch

  mamba_k<<<dim3(4096), dim3(64), 0, stream>>>(xg, lwg, lbg, ipwg, cwg, cbg, xpwg,
                                               dtwg, dtbg, alogg, dskg, owg, bwg, bbg, feat);
  ln_k<<<dim3(512), dim3(64), 0, stream>>>(feat, lng, lnb, (float*)d_out);
}